// Round 9
// baseline (2292.697 us; speedup 1.0000x reference)
//
#include <hip/hip_runtime.h>
#include <stdint.h>

// SSMTrack: B=8, S=4096, H=1024, D=256
// One fused launch: 8 scan blocks (pure, barrier-locked internally only) +
// 240 persistent GEMM worker blocks on OTHER CUs, coupled via device-scope
// flags. gemm1 feeds the scan per-128-row chunk; gemm3 trails the scan's
// published progress. No GEMM work inside scan blocks (R5-R7 refuted that).

typedef float v4f __attribute__((ext_vector_type(4)));
typedef __bf16 bf16x4 __attribute__((ext_vector_type(4)));
typedef __bf16 bf16x8 __attribute__((ext_vector_type(8)));
typedef _Float16 h8 __attribute__((ext_vector_type(8)));

#define BARRIER_LGKM() asm volatile("s_waitcnt lgkmcnt(0)\n\ts_barrier" ::: "memory")

#define GLOAD_LDS16(g, l)                                                    \
  __builtin_amdgcn_global_load_lds(                                          \
      (const __attribute__((address_space(1))) void*)(g),                    \
      (__attribute__((address_space(3))) void*)(l), 16, 0, 0)

// s_getreg: imm = (size-1)<<11 | offset<<6 | id.  HW_ID id=4, XCC_ID id=20.
#define GETREG_HWID  __builtin_amdgcn_s_getreg(0xF804)
#define GETREG_XCCID __builtin_amdgcn_s_getreg(0xF814)

#define AT_LOAD(p)     __hip_atomic_load((p), __ATOMIC_RELAXED, __HIP_MEMORY_SCOPE_AGENT)
#define AT_STORE(p, v) __hip_atomic_store((p), (v), __ATOMIC_RELAXED, __HIP_MEMORY_SCOPE_AGENT)
#define AT_ADD(p, v)   __hip_atomic_fetch_add((p), (v), __ATOMIC_RELAXED, __HIP_MEMORY_SCOPE_AGENT)
#define FENCE_ACQ() __builtin_amdgcn_fence(__ATOMIC_ACQUIRE, "agent")
#define FENCE_REL() __builtin_amdgcn_fence(__ATOMIC_RELEASE, "agent")

// ctl layout (u32): [0]=pair counter  [1]=scan-reg count  [2..9]=progress[8]
// [10..17]=scanCU[8]  [18]=exit count  [32..287]=g1flag[256]
#define CTL_NEXT 0
#define CTL_REG  1
#define CTL_PROG 2
#define CTL_SCU  10
#define CTL_EXIT 18
#define CTL_G1   32

// ---------------------------------------------------------------- conversions
__global__ void cvt_f32_bf16_x4(const float* __restrict__ in,
                                __bf16* __restrict__ out, int n4) {
  int i = blockIdx.x * blockDim.x + threadIdx.x;
  if (i >= n4) return;
  v4f v = ((const v4f*)in)[i];
  bf16x4 o;
  o.x = (__bf16)v.x; o.y = (__bf16)v.y; o.z = (__bf16)v.z; o.w = (__bf16)v.w;
  ((bf16x4*)out)[i] = o;
}

__global__ void transpose_cvt(const float* __restrict__ in,
                              __bf16* __restrict__ out, int K, int N) {
  int i = blockIdx.x * blockDim.x + threadIdx.x;
  if (i >= K * N) return;
  int k = i / N;
  int n = i - k * N;
  out[(size_t)n * K + k] = (__bf16)in[i];
}

__global__ void zero_ctl(uint32_t* p) { p[threadIdx.x] = 0; }

// ---------------------------------------------------------------- gemm 128x128
// Proven body (R2-R8): BK=32, 4 waves (2x2), 4x4 frags of 16x16x32 MFMA,
// double-buffered LDS via global_load_lds(16B), source-side swizzle.
// tid is 0..255 within the subgroup; lds is this subgroup's 32KB.
// NOTE: __syncthreads() syncs the whole 512-thread block; both subgroups run
// identical schedules (same K), so barrier counts match.
__device__ __forceinline__ void gemm128(
    const __bf16* __restrict__ A, const __bf16* __restrict__ Bt,
    const float* __restrict__ bias, float* __restrict__ C,
    int N, int K, int m0, int n0, char* lds, int tid) {
  const int lane = tid & 63;
  const int w = tid >> 6;          // 0..3
  const int wr = w >> 1, wc = w & 1;
  const int r = lane & 15, q = lane >> 4;

  const __bf16* gA[2];
  const __bf16* gB[2];
  int loff[2];
#pragma unroll
  for (int j = 0; j < 2; ++j) {
    int o = (w * 2 + j) * 1024 + lane * 16;
    int row = o >> 6;
    int s = (o >> 4) & 3;
    int ss = s ^ ((row >> 1) & 3);
    gA[j] = A + (size_t)(m0 + row) * K + ss * 8;
    gB[j] = Bt + (size_t)(n0 + row) * K + ss * 8;
    loff[j] = (w * 2 + j) * 1024;
  }

  const int slot = (q ^ ((r >> 1) & 3)) * 16;
  int aoff[4], boff[4];
#pragma unroll
  for (int i = 0; i < 4; ++i) {
    aoff[i] = (wr * 64 + i * 16 + r) * 64 + slot;
    boff[i] = 8192 + (wc * 64 + i * 16 + r) * 64 + slot;
  }

  v4f acc[4][4];
#pragma unroll
  for (int mi = 0; mi < 4; ++mi)
#pragma unroll
    for (int ni = 0; ni < 4; ++ni) acc[mi][ni] = (v4f){0.f, 0.f, 0.f, 0.f};

  const int NK = K >> 5;
#pragma unroll
  for (int j = 0; j < 2; ++j) {
    GLOAD_LDS16(gA[j], lds + loff[j]);
    GLOAD_LDS16(gB[j], lds + 8192 + loff[j]);
  }

  for (int kt = 0; kt < NK; ++kt) {
    __syncthreads();
    if (kt + 1 < NK) {
      char* lb = lds + ((kt + 1) & 1) * 16384;
      const int ke = (kt + 1) * 32;
#pragma unroll
      for (int j = 0; j < 2; ++j) {
        GLOAD_LDS16(gA[j] + ke, lb + loff[j]);
        GLOAD_LDS16(gB[j] + ke, lb + 8192 + loff[j]);
      }
    }
    const char* Lb = lds + (kt & 1) * 16384;
    bf16x8 af[4], bf[4];
#pragma unroll
    for (int i = 0; i < 4; ++i) af[i] = *(const bf16x8*)(Lb + aoff[i]);
#pragma unroll
    for (int i = 0; i < 4; ++i) bf[i] = *(const bf16x8*)(Lb + boff[i]);
#pragma unroll
    for (int mi = 0; mi < 4; ++mi)
#pragma unroll
      for (int ni = 0; ni < 4; ++ni)
        acc[mi][ni] = __builtin_amdgcn_mfma_f32_16x16x32_bf16(
            af[mi], bf[ni], acc[mi][ni], 0, 0, 0);
  }

  float bv[4];
#pragma unroll
  for (int ni = 0; ni < 4; ++ni) bv[ni] = bias[n0 + wc * 64 + ni * 16 + r];
#pragma unroll
  for (int mi = 0; mi < 4; ++mi) {
    int rowb = m0 + wr * 64 + mi * 16 + q * 4;
#pragma unroll
    for (int ni = 0; ni < 4; ++ni) {
      int col = n0 + wc * 64 + ni * 16 + r;
      float* cp = C + (size_t)rowb * N + col;
#pragma unroll
      for (int i = 0; i < 4; ++i) cp[(size_t)i * N] = acc[mi][ni][i] + bv[ni];
    }
  }
}

// ---------------------------------------------------------------- fused
// Blocks 0..7: scan (R4 structure, 8 waves). Blocks 8..247: workers.
// Work queue (pairs of 128x128 tiles; P uniform per worker block):
//   P <  256 : gemm1 pair  (c=P>>3, b=P&7; n0 = sub*128)   -> sets g1flag[P]
//   P >= 256 : gemm3 pair  (Q=P-256: mc=Q>>5, b=(Q>>2)&7, np=Q&3;
//              n0=(np*2+sub)*128) -> waits progress[b] >= 128*(mc+1)
// Scan waits g1flag[c*8+b] before prefetching chunk c; publishes progress[b]
// every 128 steps with vmcnt(0)+release fence. Workers landing on a scan CU
// self-evict (s_getreg HW_ID/XCC_ID), capped at 16 exits (deadlock hedge).
__global__ __launch_bounds__(512) void fused(
    const __bf16* __restrict__ xb,      // [M,1024] bf16
    const __bf16* __restrict__ WinT,    // [256,1024] bf16
    const float* __restrict__ b_in,     // [256]
    float* __restrict__ inp,            // [M,256] f32
    const float* __restrict__ Wst,      // [256,256] f32
    const float* __restrict__ b_state,  // [256]
    __bf16* __restrict__ states,        // [M,256] bf16
    const __bf16* __restrict__ WoutT,   // [1024,256] bf16
    const float* __restrict__ b_out,    // [1024]
    float* __restrict__ out,            // [M,1024] f32
    uint32_t* __restrict__ ctl, int S) {
  const int tid = threadIdx.x;
  __shared__ __align__(16) char ldsAll[65552];

  uint32_t* progress = ctl + CTL_PROG;
  uint32_t* scanCU = ctl + CTL_SCU;
  uint32_t* g1flag = ctl + CTL_G1;

  if (blockIdx.x < 8) {
    // ============================================================ scan role
    const int b = blockIdx.x;
    const int l = tid & 63;
    const int q = l >> 4;
    const int r = l & 15;
    const int w = tid >> 6;  // 0..7

    if (tid == 0) {
      uint32_t id = ((GETREG_HWID >> 8) & 0xFF) | (GETREG_XCCID << 8);
      AT_STORE(&scanCU[b], id);
      __hip_atomic_fetch_add(&ctl[CTL_REG], 1u, __ATOMIC_RELEASE,
                             __HIP_MEMORY_SCOPE_AGENT);
    }

    // W_state B-fragments (tiles 2w, 2w+1): lane holds B[k][col],
    // col = 32w + 16j + r, k = 32c + 8q + i.
    h8 bwA[8], bwB[8];
#pragma unroll
    for (int c = 0; c < 8; ++c) {
#pragma unroll
      for (int i = 0; i < 8; ++i) {
        const float* wp = Wst + (size_t)(32 * c + 8 * q + i) * 256 + 32 * w + r;
        bwA[c][i] = (_Float16)wp[0];
        bwB[c][i] = (_Float16)wp[16];
      }
    }

    const int col = 32 * w + 16 * (q & 1) + r;
    const float bst = b_state[col];
    const float* inpb = inp + (size_t)b * S * 256;
    __bf16* stb = states + (size_t)b * S * 256;

    // wait for inp chunk 0 (rows 0..127 of this batch)
    if (tid == 0) {
      while (AT_LOAD(&g1flag[b]) == 0) __builtin_amdgcn_s_sleep(8);
    }
    __syncthreads();
    FENCE_ACQ();

    _Float16* sbuf = (_Float16*)ldsAll;  // [2][256]
    if (tid < 256) sbuf[tid] = (_Float16)0.f;
    float u_cur = inpb[col];
    float u_nxt = inpb[256 + col];
    __syncthreads();

    int cur = 0;
    for (int t = 0; t < S; ++t) {
      if ((t + 2 < S) && (((t + 2) & 127) == 0)) {
        const int c = (t + 2) >> 7;
        if (tid == 0) {
          while (AT_LOAD(&g1flag[c * 8 + b]) == 0) __builtin_amdgcn_s_sleep(8);
        }
        __syncthreads();
        FENCE_ACQ();
      }
      float u_n2 = 0.f;
      if (t + 2 < S) u_n2 = inpb[(size_t)(t + 2) * 256 + col];

      const h8* sp = (const h8*)(ldsAll + cur * 512);
      h8 af[8];
#pragma unroll
      for (int c = 0; c < 8; ++c) af[c] = sp[4 * c + q];

      v4f a0 = {0.f, 0.f, 0.f, 0.f};
      v4f a1 = a0;
#pragma unroll
      for (int c = 0; c < 8; ++c) {
        a0 = __builtin_amdgcn_mfma_f32_16x16x32_f16(af[c], bwA[c], a0, 0, 0, 0);
        a1 = __builtin_amdgcn_mfma_f32_16x16x32_f16(af[c], bwB[c], a1, 0, 0, 0);
      }
      float x = ((q & 1) ? a1[0] : a0[0]) + u_cur + bst;

      float e = exp2f(2.885390082f * x);
      float sn = 1.f - 2.f * __builtin_amdgcn_rcpf(e + 1.f);

      cur ^= 1;
      if (q < 2) {
        ((_Float16*)ldsAll)[cur * 256 + col] = (_Float16)sn;
        stb[(size_t)t * 256 + col] = (__bf16)sn;
      }
      if ((t & 127) == 127) {  // publish progress = t+1
        asm volatile("s_waitcnt vmcnt(0)" ::: "memory");
        __syncthreads();
        if (tid == 0) {
          FENCE_REL();
          AT_STORE(&progress[b], (uint32_t)(t + 1));
        }
      }
      u_cur = u_nxt;
      u_nxt = u_n2;
      BARRIER_LGKM();
    }
  } else {
    // ============================================================ worker role
    volatile uint32_t* bc = (volatile uint32_t*)(ldsAll + 65536);
    if (tid == 0) {
      while (__hip_atomic_load(&ctl[CTL_REG], __ATOMIC_ACQUIRE,
                               __HIP_MEMORY_SCOPE_AGENT) < 8)
        __builtin_amdgcn_s_sleep(8);
      uint32_t id = ((GETREG_HWID >> 8) & 0xFF) | (GETREG_XCCID << 8);
      uint32_t clash = 0;
#pragma unroll
      for (int i = 0; i < 8; ++i)
        if (AT_LOAD(&scanCU[i]) == id) clash = 1;
      uint32_t doexit = 0;
      if (clash && AT_ADD(&ctl[CTL_EXIT], 1u) < 16) doexit = 1;
      *bc = doexit;
    }
    __syncthreads();
    if (*bc) return;  // vacate scan CU (capped -> no deadlock)

    const int sub = tid >> 8;   // 0/1
    const int stid = tid & 255;
    char* myl = ldsAll + sub * 32768;

    for (;;) {
      __syncthreads();  // protect bc reuse + LDS reuse across pairs
      if (tid == 0) *bc = AT_ADD(&ctl[CTL_NEXT], 1u);
      __syncthreads();
      uint32_t P = *bc;
      if (P >= 1280) return;

      if (P < 256) {
        // gemm1: inp = xb @ W_in + b_in   (chunk c of batch b)
        const int c = P >> 3, b = P & 7;
        const int m0 = b * 4096 + c * 128;
        gemm128(xb, WinT, b_in, inp, 256, 1024, m0, sub * 128, myl, stid);
        asm volatile("s_waitcnt vmcnt(0)" ::: "memory");
        __syncthreads();
        if (tid == 0) {
          FENCE_REL();
          AT_STORE(&g1flag[P], 1u);
        }
      } else {
        // gemm3: out = states @ W_out + b_out
        const uint32_t Q = P - 256;
        const int mc = Q >> 5, b = (Q >> 2) & 7, np = Q & 3;
        if (tid == 0) {
          const uint32_t need = (uint32_t)(mc + 1) * 128;
          while (AT_LOAD(&progress[b]) < need) __builtin_amdgcn_s_sleep(64);
        }
        __syncthreads();
        FENCE_ACQ();
        const int m0 = b * 4096 + mc * 128;
        gemm128(states, WoutT, b_out, out, 1024, 256, m0,
                (np * 2 + sub) * 128, myl, stid);
      }
    }
  }
}

// ---------------------------------------------------------------- launch
extern "C" void kernel_launch(void* const* d_in, const int* in_sizes, int n_in,
                              void* d_out, int out_size, void* d_ws,
                              size_t ws_size, hipStream_t stream) {
  const float* x       = (const float*)d_in[0];  // [8,4096,1024]
  const float* W_in    = (const float*)d_in[1];  // [1024,256]
  const float* b_in    = (const float*)d_in[2];  // [256]
  const float* W_state = (const float*)d_in[3];  // [256,256]
  const float* b_state = (const float*)d_in[4];  // [256]
  const float* W_out   = (const float*)d_in[5];  // [256,1024]
  const float* b_out   = (const float*)d_in[6];  // [1024]
  float* out = (float*)d_out;                    // [8,4096,1024]

  const int B = 8, S = 4096, H = 1024, D = 256;
  const int M = B * S;  // 32768

  char* ws = (char*)d_ws;
  float*  inp    = (float*)(ws + 0);            // 32 MB  [M,D] f32
  __bf16* states = (__bf16*)(ws + 33554432);    // 16 MB  [M,D] bf16
  __bf16* xb     = (__bf16*)(ws + 50331648);    // 64 MB  [M,H] bf16
  __bf16* WinT   = (__bf16*)(ws + 117440512);   // 0.5 MB [D,H] bf16  (W_in^T)
  __bf16* WoutT  = (__bf16*)(ws + 117964800);   // 0.5 MB [H,D] bf16  (W_out^T)
  uint32_t* ctl  = (uint32_t*)(ws + 118489088); // 2 KB   control flags

  // conversions
  cvt_f32_bf16_x4<<<(M * H / 4 + 255) / 256, 256, 0, stream>>>(x, xb, M * H / 4);
  transpose_cvt<<<(H * D + 255) / 256, 256, 0, stream>>>(W_in, WinT, H, D);
  transpose_cvt<<<(D * H + 255) / 256, 256, 0, stream>>>(W_out, WoutT, D, H);
  zero_ctl<<<1, 512, 0, stream>>>(ctl);

  // fused: 8 scan blocks + 240 persistent GEMM workers
  fused<<<248, 512, 0, stream>>>(xb, WinT, b_in, inp, W_state, b_state,
                                 states, WoutT, b_out, out, ctl, S);
}

// Round 10
// 2105.416 us; speedup vs baseline: 1.0890x; 1.0890x over previous
//
#include <hip/hip_runtime.h>
#include <stdint.h>

// SSMTrack: B=8, S=4096, H=1024, D=256
//   inp = x @ W_in + b_in          (gemm_xa: f32-A reg-staged bf16 MFMA GEMM)
//   s_t = tanh(inp_t + s_{t-1} @ W_state + b_state)   (MFMA f16 scan, R8 structure)
//   out = states @ W_out + b_out   (gemm_tile, unchanged)
//
// History: scan step = 1066 cy invariant across 5 structures (~507 MFMA pipe
// + ~250 broadcast-DS + ~300 latency tail). Concurrent-work schemes (R5-R7
// in-block, R9 flag-coupled workers) all lost >= the ~230 us they could
// absorb -> abandoned per pre-commitment. This round shaves the serial
// non-scan chain: cvt dispatch + xb buffer eliminated, transposes fused.

typedef float v4f __attribute__((ext_vector_type(4)));
typedef __bf16 bf16x8 __attribute__((ext_vector_type(8)));
typedef _Float16 h8 __attribute__((ext_vector_type(8)));

#define BARRIER_LGKM() asm volatile("s_waitcnt lgkmcnt(0)\n\ts_barrier" ::: "memory")

#define GLOAD_LDS16(g, l)                                                    \
  __builtin_amdgcn_global_load_lds(                                          \
      (const __attribute__((address_space(1))) void*)(g),                    \
      (__attribute__((address_space(3))) void*)(l), 16, 0, 0)

// ---------------------------------------------------------------- transposes
// W_in [1024,256] -> WinT [256,1024] bf16;  W_out [256,1024] -> WoutT [1024,256] bf16
__global__ void transpose_cvt2(const float* __restrict__ W_in,
                               __bf16* __restrict__ WinT,
                               const float* __restrict__ W_out,
                               __bf16* __restrict__ WoutT) {
  int i = blockIdx.x * blockDim.x + threadIdx.x;
  if (i < 1024 * 256) {
    int k = i >> 8, n = i & 255;
    WinT[(size_t)n * 1024 + k] = (__bf16)W_in[i];
  } else {
    int j = i - 1024 * 256;
    int k = j >> 10, n = j & 1023;
    WoutT[(size_t)n * 256 + k] = (__bf16)W_out[j];
  }
}

// ---------------------------------------------------------------- gemm (bf16 A)
// C[M,N](f32) = A[M,K](bf16 rm) * B + bias, Bt[N,K] = B^T (bf16 rm).
// Proven body (R2-R8): 128x128 tile, BK=32, 4 waves (2x2), 4x4 frags of
// 16x16x32 MFMA, double-buffered LDS via global_load_lds(16B), source-side
// swizzle slot^((row>>1)&3), one barrier per K-step.
__global__ __launch_bounds__(256) void gemm_tile(
    const __bf16* __restrict__ A, const __bf16* __restrict__ Bt,
    const float* __restrict__ bias, float* __restrict__ C,
    int M, int N, int K) {
  const int tid = threadIdx.x;
  const int lane = tid & 63;
  const int w = tid >> 6;
  const int wr = w >> 1, wc = w & 1;
  const int r = lane & 15, q = lane >> 4;

  const int nbn = N >> 7;
  const int mb = blockIdx.x / nbn;
  const int nb = blockIdx.x - mb * nbn;
  const int m0 = mb << 7, n0 = nb << 7;

  __shared__ __align__(16) char lds[2][16384];

  const __bf16* gA[2];
  const __bf16* gB[2];
  int loff[2];
#pragma unroll
  for (int j = 0; j < 2; ++j) {
    int o = (w * 2 + j) * 1024 + lane * 16;
    int row = o >> 6;
    int s = (o >> 4) & 3;
    int ss = s ^ ((row >> 1) & 3);
    gA[j] = A + (size_t)(m0 + row) * K + ss * 8;
    gB[j] = Bt + (size_t)(n0 + row) * K + ss * 8;
    loff[j] = (w * 2 + j) * 1024;
  }

  const int slot = (q ^ ((r >> 1) & 3)) * 16;
  int aoff[4], boff[4];
#pragma unroll
  for (int i = 0; i < 4; ++i) {
    aoff[i] = (wr * 64 + i * 16 + r) * 64 + slot;
    boff[i] = 8192 + (wc * 64 + i * 16 + r) * 64 + slot;
  }

  v4f acc[4][4];
#pragma unroll
  for (int mi = 0; mi < 4; ++mi)
#pragma unroll
    for (int ni = 0; ni < 4; ++ni) acc[mi][ni] = (v4f){0.f, 0.f, 0.f, 0.f};

  const int NK = K >> 5;
#pragma unroll
  for (int j = 0; j < 2; ++j) {
    GLOAD_LDS16(gA[j], lds[0] + loff[j]);
    GLOAD_LDS16(gB[j], lds[0] + 8192 + loff[j]);
  }

  for (int kt = 0; kt < NK; ++kt) {
    __syncthreads();
    if (kt + 1 < NK) {
      const int bb = (kt + 1) & 1;
      const int ke = (kt + 1) * 32;
#pragma unroll
      for (int j = 0; j < 2; ++j) {
        GLOAD_LDS16(gA[j] + ke, lds[bb] + loff[j]);
        GLOAD_LDS16(gB[j] + ke, lds[bb] + 8192 + loff[j]);
      }
    }
    const char* Lb = lds[kt & 1];
    bf16x8 af[4], bf[4];
#pragma unroll
    for (int i = 0; i < 4; ++i) af[i] = *(const bf16x8*)(Lb + aoff[i]);
#pragma unroll
    for (int i = 0; i < 4; ++i) bf[i] = *(const bf16x8*)(Lb + boff[i]);
#pragma unroll
    for (int mi = 0; mi < 4; ++mi)
#pragma unroll
      for (int ni = 0; ni < 4; ++ni)
        acc[mi][ni] = __builtin_amdgcn_mfma_f32_16x16x32_bf16(
            af[mi], bf[ni], acc[mi][ni], 0, 0, 0);
  }

  float bv[4];
#pragma unroll
  for (int ni = 0; ni < 4; ++ni) bv[ni] = bias[n0 + wc * 64 + ni * 16 + r];
#pragma unroll
  for (int mi = 0; mi < 4; ++mi) {
    int rowb = m0 + wr * 64 + mi * 16 + q * 4;
#pragma unroll
    for (int ni = 0; ni < 4; ++ni) {
      int col = n0 + wc * 64 + ni * 16 + r;
      float* cp = C + (size_t)rowb * N + col;
#pragma unroll
      for (int i = 0; i < 4; ++i) cp[(size_t)i * N] = acc[mi][ni][i] + bv[ni];
    }
  }
}

// ---------------------------------------------------------------- gemm (f32 A)
// Same as gemm_tile but A is f32 (the raw x): A-tile is reg-staged
// (4x global_load_dwordx4 -> cvt -> 2x ds_write_b128) into the SAME swizzled
// bf16 LDS layout, so the read side + MFMA loop are byte-identical to
// gemm_tile. Thread t stages row = t>>1, half h = t&1: LDS slot s in
// {2h,2h+1} holds global 8-float group s^((row>>1)&3) -> read slot
// q^((r>>1)&3) fetches global group q, exactly as the proven kernel.
// Eliminates the separate x->bf16 cvt kernel and the 64MB xb buffer.
__global__ __launch_bounds__(256) void gemm_xa(
    const float* __restrict__ A,     // [M,K] f32 (x)
    const __bf16* __restrict__ Bt,   // [N,K] bf16
    const float* __restrict__ bias, float* __restrict__ C,
    int M, int N, int K) {
  const int tid = threadIdx.x;
  const int lane = tid & 63;
  const int w = tid >> 6;
  const int wr = w >> 1, wc = w & 1;
  const int r = lane & 15, q = lane >> 4;

  const int nbn = N >> 7;
  const int mb = blockIdx.x / nbn;
  const int nb = blockIdx.x - mb * nbn;
  const int m0 = mb << 7, n0 = nb << 7;

  __shared__ __align__(16) char lds[2][16384];  // [buf][A-bf16 8K | B 8K]

  // ---- A reg-staging geometry (per thread)
  const int arow = tid >> 1;            // 0..127
  const int h = tid & 1;
  const int sw = (arow >> 1) & 3;
  const int g0 = (2 * h) ^ sw;          // global 8-float group for LDS slot 2h
  const int g1 = (2 * h + 1) ^ sw;      // for LDS slot 2h+1
  const float* gAsrc = A + (size_t)(m0 + arow) * K;
  const int awoff = arow * 64 + 2 * h * 16;  // LDS byte offset of slot 2h

  // ---- B staging via global_load_lds (unchanged)
  const __bf16* gB[2];
  int loffB[2];
#pragma unroll
  for (int j = 0; j < 2; ++j) {
    int o = (w * 2 + j) * 1024 + lane * 16;
    int row = o >> 6;
    int s = (o >> 4) & 3;
    int ss = s ^ ((row >> 1) & 3);
    gB[j] = Bt + (size_t)(n0 + row) * K + ss * 8;
    loffB[j] = 8192 + (w * 2 + j) * 1024;
  }

  const int slot = (q ^ ((r >> 1) & 3)) * 16;
  int aoff[4], boff[4];
#pragma unroll
  for (int i = 0; i < 4; ++i) {
    aoff[i] = (wr * 64 + i * 16 + r) * 64 + slot;
    boff[i] = 8192 + (wc * 64 + i * 16 + r) * 64 + slot;
  }

  v4f acc[4][4];
#pragma unroll
  for (int mi = 0; mi < 4; ++mi)
#pragma unroll
    for (int ni = 0; ni < 4; ++ni) acc[mi][ni] = (v4f){0.f, 0.f, 0.f, 0.f};

  const int NK = K >> 5;

  // prologue: stage A(0) via regs + B(0) via gload_lds into buf0
  {
    v4f a0 = *(const v4f*)(gAsrc + g0 * 8);
    v4f a1 = *(const v4f*)(gAsrc + g0 * 8 + 4);
    v4f a2 = *(const v4f*)(gAsrc + g1 * 8);
    v4f a3 = *(const v4f*)(gAsrc + g1 * 8 + 4);
#pragma unroll
    for (int j = 0; j < 2; ++j) GLOAD_LDS16(gB[j], lds[0] + loffB[j]);
    bf16x8 w0, w1;
#pragma unroll
    for (int i = 0; i < 4; ++i) {
      w0[i] = (__bf16)a0[i]; w0[4 + i] = (__bf16)a1[i];
      w1[i] = (__bf16)a2[i]; w1[4 + i] = (__bf16)a3[i];
    }
    *(bf16x8*)(lds[0] + awoff) = w0;
    *(bf16x8*)(lds[0] + awoff + 16) = w1;
  }

  for (int kt = 0; kt < NK; ++kt) {
    __syncthreads();  // buf[kt] complete (A ds_writes + B gload_lds drained)
    const int nxt = kt + 1;
    v4f a0, a1, a2, a3;
    if (nxt < NK) {
      const float* s = gAsrc + nxt * 32;
      a0 = *(const v4f*)(s + g0 * 8);
      a1 = *(const v4f*)(s + g0 * 8 + 4);
      a2 = *(const v4f*)(s + g1 * 8);
      a3 = *(const v4f*)(s + g1 * 8 + 4);
#pragma unroll
      for (int j = 0; j < 2; ++j)
        GLOAD_LDS16(gB[j] + nxt * 32, lds[nxt & 1] + loffB[j]);
    }
    const char* Lb = lds[kt & 1];
    bf16x8 af[4], bf[4];
#pragma unroll
    for (int i = 0; i < 4; ++i) af[i] = *(const bf16x8*)(Lb + aoff[i]);
#pragma unroll
    for (int i = 0; i < 4; ++i) bf[i] = *(const bf16x8*)(Lb + boff[i]);
#pragma unroll
    for (int mi = 0; mi < 4; ++mi)
#pragma unroll
      for (int ni = 0; ni < 4; ++ni)
        acc[mi][ni] = __builtin_amdgcn_mfma_f32_16x16x32_bf16(
            af[mi], bf[ni], acc[mi][ni], 0, 0, 0);
    if (nxt < NK) {  // cvt + write next A-tile (loads had the MFMA section to land)
      bf16x8 w0, w1;
#pragma unroll
      for (int i = 0; i < 4; ++i) {
        w0[i] = (__bf16)a0[i]; w0[4 + i] = (__bf16)a1[i];
        w1[i] = (__bf16)a2[i]; w1[4 + i] = (__bf16)a3[i];
      }
      char* Ln = lds[nxt & 1];
      *(bf16x8*)(Ln + awoff) = w0;
      *(bf16x8*)(Ln + awoff + 16) = w1;
    }
  }

  float bv[4];
#pragma unroll
  for (int ni = 0; ni < 4; ++ni) bv[ni] = bias[n0 + wc * 64 + ni * 16 + r];
#pragma unroll
  for (int mi = 0; mi < 4; ++mi) {
    int rowb = m0 + wr * 64 + mi * 16 + q * 4;
#pragma unroll
    for (int ni = 0; ni < 4; ++ni) {
      int col = n0 + wc * 64 + ni * 16 + r;
      float* cp = C + (size_t)rowb * N + col;
#pragma unroll
      for (int i = 0; i < 4; ++i) cp[(size_t)i * N] = acc[mi][ni][i] + bv[ni];
    }
  }
}

// ---------------------------------------------------------------- scan (MFMA)
// R8 structure, measured 1820 us (step ~1066 cy, invariant floor).
// 1024 threads = 16 waves = 4 waves/SIMD; wave w owns one 16-col tile
// (32-VGPR W-frag, two depth-4 MFMA chains); all 16 A-rows alias the state
// vector (4-address broadcast LDS read); writers q==0; one lgkm barrier/step.
__global__ __launch_bounds__(1024) void scan_mfma(
    const float* __restrict__ inp,      // [B*S, 256] f32
    const float* __restrict__ Wst,      // [256, 256] f32
    const float* __restrict__ b_state,  // [256] f32
    __bf16* __restrict__ states,        // [B*S, 256] bf16 (out)
    int S) {
  const int tid = threadIdx.x;
  const int l = tid & 63;
  const int q = l >> 4;
  const int r = l & 15;
  const int w = tid >> 6;             // wave 0..15
  const int b = blockIdx.x;

  __shared__ __align__(16) _Float16 sbuf[2][256];

  h8 bw[8];
#pragma unroll
  for (int c = 0; c < 8; ++c) {
#pragma unroll
    for (int i = 0; i < 8; ++i)
      bw[c][i] = (_Float16)Wst[(size_t)(32 * c + 8 * q + i) * 256 + 16 * w + r];
  }

  const int col = 16 * w + r;
  const float bst = b_state[col];
  const float* inpb = inp + (size_t)b * S * 256;
  __bf16* stb = states + (size_t)b * S * 256;

  if (tid < 256) sbuf[0][tid] = (_Float16)0.f;
  float u_cur = inpb[col];
  float u_nxt = inpb[256 + col];
  __syncthreads();

  int cur = 0;
  for (int t = 0; t < S; ++t) {
    float u_n2 = 0.f;
    if (t + 2 < S) u_n2 = inpb[(size_t)(t + 2) * 256 + col];

    const h8* sp = (const h8*)sbuf[cur];
    h8 af[8];
#pragma unroll
    for (int c = 0; c < 8; ++c) af[c] = sp[4 * c + q];

    v4f accE = {0.f, 0.f, 0.f, 0.f};
    v4f accO = accE;
#pragma unroll
    for (int c = 0; c < 4; ++c) {
      accE = __builtin_amdgcn_mfma_f32_16x16x32_f16(af[2 * c],     bw[2 * c],     accE, 0, 0, 0);
      accO = __builtin_amdgcn_mfma_f32_16x16x32_f16(af[2 * c + 1], bw[2 * c + 1], accO, 0, 0, 0);
    }
    float x = accE[0] + accO[0] + u_cur + bst;

    float e = exp2f(2.885390082f * x);
    float sn = 1.f - 2.f * __builtin_amdgcn_rcpf(e + 1.f);

    cur ^= 1;
    if (q == 0) {
      sbuf[cur][col] = (_Float16)sn;
      stb[(size_t)t * 256 + col] = (__bf16)sn;
    }
    u_cur = u_nxt;
    u_nxt = u_n2;
    BARRIER_LGKM();
  }
}

// ---------------------------------------------------------------- launch
extern "C" void kernel_launch(void* const* d_in, const int* in_sizes, int n_in,
                              void* d_out, int out_size, void* d_ws,
                              size_t ws_size, hipStream_t stream) {
  const float* x       = (const float*)d_in[0];  // [8,4096,1024]
  const float* W_in    = (const float*)d_in[1];  // [1024,256]
  const float* b_in    = (const float*)d_in[2];  // [256]
  const float* W_state = (const float*)d_in[3];  // [256,256]
  const float* b_state = (const float*)d_in[4];  // [256]
  const float* W_out   = (const float*)d_in[5];  // [256,1024]
  const float* b_out   = (const float*)d_in[6];  // [1024]
  float* out = (float*)d_out;                    // [8,4096,1024]

  const int B = 8, S = 4096, H = 1024, D = 256;
  const int M = B * S;  // 32768

  char* ws = (char*)d_ws;
  float*  inp    = (float*)(ws + 0);            // 32 MB  [M,D] f32
  __bf16* states = (__bf16*)(ws + 33554432);    // 16 MB  [M,D] bf16
  __bf16* WinT   = (__bf16*)(ws + 50331648);    // 0.5 MB [D,H] bf16  (W_in^T)
  __bf16* WoutT  = (__bf16*)(ws + 50855936);    // 0.5 MB [H,D] bf16  (W_out^T)

  // both weight transposes in one dispatch
  transpose_cvt2<<<2048, 256, 0, stream>>>(W_in, WinT, W_out, WoutT);

  // phase 1: inp = x @ W_in + b_in  (f32 A read directly; no cvt pass)
  gemm_xa<<<(M / 128) * (D / 128), 256, 0, stream>>>(x, WinT, b_in, inp, M, D, H);

  // phase 2: sequential scan, one block (16 waves) per batch
  scan_mfma<<<B, 1024, 0, stream>>>(inp, W_state, b_state, states, S);

  // phase 3: out = states @ W_out + b_out
  gemm_tile<<<(M / 128) * (H / 128), 256, 0, stream>>>(states, WoutT, b_out, out, M, H, D);
}